// Round 11
// baseline (4194.381 us; speedup 1.0000x reference)
//
#include <hip/hip_runtime.h>

#define ITERS 8  // m's per block; grid = M/ITERS = 2048 -> 8 blocks/CU, 4 resident

// Async global->LDS, 16B per lane. Dest = wave-uniform base + lane*16.
__device__ __forceinline__ void gload_lds16(const float* g, float* l) {
  __builtin_amdgcn_global_load_lds(
      (const __attribute__((address_space(1))) unsigned int*)g,
      (__attribute__((address_space(3))) unsigned int*)l, 16, 0, 0);
}

// ---------------- K1: sim + dual softmax + heatmap + argmax ----------------
// R5 compute structure (4x4 tile, [half][row][32] LDS, src-side XOR swizzle
// e(p)=(p>>2)&7), but ITERS m's per block with a rolling in-place pipeline:
// after a half-buffer is consumed (barrier), the NEXT m's same half is staged
// into it. Counted vmcnt discipline (never 0 after it=0):
//   W1 (h0(m) ready):  ops issued after h0(m) = stage_h1(m) 4 + heat(m-1) 4
//                      -> vmcnt(8)   [it=0: 4]
//   W3 (h1(m) ready):  ops issued after h1(m) = heat(m-1) 4
//                      -> vmcnt(4)   [it=0: 0]
// Heatmap stores are never waited on. Scalar outputs are deferred to a
// register pack (2x u64) and written after the loop so per-wave VM-queue
// symmetry is preserved.
__global__ __launch_bounds__(256, 4) void fm_main_kernel(
    const float* __restrict__ feat0, const float* __restrict__ feat1,
    float* __restrict__ out, int M)
{
  const int t    = threadIdx.x;
  const int lane = t & 63;
  const int wave = t >> 6;

  __shared__ __align__(16) float sA[4096];      // [2][64][32] halves of cls_f0
  __shared__ __align__(16) float sB[4096];      // [2][64][32] halves of cls_f1 inner
  __shared__ __align__(16) float colps[4][64];  // per-wave col-sum partials
  __shared__ float redv[4];
  __shared__ int   redi[4];

  const int m0 = blockIdx.x * ITERS;

  const int pr = lane >> 3;   // row within 8-row chunk
  const int q  = lane & 7;    // slot quad within half

  auto stage_half = [&](int m, int h) {   // 4 VM ops per wave
    const float* f0m = feat0 + (size_t)m * 8192;   // 64*128
    const float* f1m = feat1 + (size_t)m * 12800;  // 100*128
#pragma unroll
    for (int k = 0; k < 2; ++k) {
      const int p0 = wave * 16 + k * 8;
      const int p  = p0 + pr;
      const int gq = q ^ ((p >> 2) & 7);                // source-side swizzle
      gload_lds16(f0m + p * 128 + h * 32 + gq * 4, &sA[h * 2048 + p0 * 32]);
      const int r = ((p >> 3) + 1) * 10 + (p & 7) + 1;  // inner 8x8 of 10x10
      gload_lds16(f1m + r * 128 + h * 32 + gq * 4, &sB[h * 2048 + p0 * 32]);
    }
  };

  const int st = t & 15, lt = t >> 4;
  const int s4 = st << 2, l4 = lt << 2;
  const int ea = lt & 7, eb = st & 7;   // read-side XOR (= e(p) of owned rows)

  unsigned long long pk0 = 0ull, pk1 = 0ull;  // deferred (i0,i1) per iteration

  // ---- prologue: stage both halves of m0 ----
  stage_half(m0, 0);
  stage_half(m0, 1);

#pragma unroll 1
  for (int it = 0; it < ITERS; ++it) {
    const int m = m0 + it;

    // W1: h0(m) landed; all waves ready
    if (it == 0) { asm volatile("s_waitcnt vmcnt(4)" ::: "memory"); }
    else         { asm volatile("s_waitcnt vmcnt(8)" ::: "memory"); }
    __builtin_amdgcn_s_barrier();
    asm volatile("" ::: "memory");

    float acc[4][4] = {};
#pragma unroll
    for (int c8 = 0; c8 < 8; ++c8) {
      const int qa = (c8 ^ ea) << 2, qb = (c8 ^ eb) << 2;
      float4 a[4], b[4];
#pragma unroll
      for (int i = 0; i < 4; ++i) a[i] = *(const float4*)(&sA[(l4 + i) * 32 + qa]);
#pragma unroll
      for (int j = 0; j < 4; ++j) b[j] = *(const float4*)(&sB[(s4 + j) * 32 + qb]);
#pragma unroll
      for (int i = 0; i < 4; ++i)
#pragma unroll
        for (int j = 0; j < 4; ++j)
          acc[i][j] += a[i].x * b[j].x + a[i].y * b[j].y + a[i].z * b[j].z + a[i].w * b[j].w;
    }

    // W3 (merged): h1(m) landed AND all waves done reading R0 (h0 region)
    if (it == 0) { asm volatile("s_waitcnt vmcnt(0)" ::: "memory"); }
    else         { asm volatile("s_waitcnt vmcnt(4)" ::: "memory"); }
    __builtin_amdgcn_s_barrier();
    asm volatile("" ::: "memory");

    if (it + 1 < ITERS) stage_half(m + 1, 0);   // -> R0 (dead), drains under h1 compute

#pragma unroll
    for (int c8 = 0; c8 < 8; ++c8) {
      const int qa = (c8 ^ ea) << 2, qb = (c8 ^ eb) << 2;
      float4 a[4], b[4];
#pragma unroll
      for (int i = 0; i < 4; ++i) a[i] = *(const float4*)(&sA[2048 + (l4 + i) * 32 + qa]);
#pragma unroll
      for (int j = 0; j < 4; ++j) b[j] = *(const float4*)(&sB[2048 + (s4 + j) * 32 + qb]);
#pragma unroll
      for (int i = 0; i < 4; ++i)
#pragma unroll
        for (int j = 0; j < 4; ++j)
          acc[i][j] += a[i].x * b[j].x + a[i].y * b[j].y + a[i].z * b[j].z + a[i].w * b[j].w;
    }

    // B4: all waves done reading R1 (h1 region)
    asm volatile("" ::: "memory");
    __builtin_amdgcn_s_barrier();
    asm volatile("" ::: "memory");

    if (it + 1 < ITERS) stage_half(m + 1, 1);   // -> R1 (dead), drains under softmax

    // ---- softmax stats, unshifted: e = exp(sim/64); heat = e^2*rinv*cinv ----
    float rinv[4];
#pragma unroll
    for (int i = 0; i < 4; ++i) {
      float rs = 0.0f;
#pragma unroll
      for (int j = 0; j < 4; ++j) { acc[i][j] = __expf(acc[i][j] * 0.015625f); rs += acc[i][j]; }
#pragma unroll
      for (int off = 1; off <= 8; off <<= 1) rs += __shfl_xor(rs, off);
      rinv[i] = 1.0f / rs;
    }
    {
      float cps[4];
#pragma unroll
      for (int j = 0; j < 4; ++j) {
        float cs = acc[0][j] + acc[1][j] + acc[2][j] + acc[3][j];
        cs += __shfl_xor(cs, 16);
        cs += __shfl_xor(cs, 32);
        cps[j] = cs;
      }
      if (lane < 16) *(float4*)(&colps[wave][s4]) = make_float4(cps[0], cps[1], cps[2], cps[3]);
    }
    asm volatile("s_waitcnt lgkmcnt(0)" ::: "memory");   // B5
    __builtin_amdgcn_s_barrier();
    asm volatile("" ::: "memory");

    float cinv[4];
    {
      float4 q0 = *(const float4*)(&colps[0][s4]);
      float4 q1 = *(const float4*)(&colps[1][s4]);
      float4 q2 = *(const float4*)(&colps[2][s4]);
      float4 q3 = *(const float4*)(&colps[3][s4]);
      cinv[0] = 1.0f / (q0.x + q1.x + q2.x + q3.x);
      cinv[1] = 1.0f / (q0.y + q1.y + q2.y + q3.y);
      cinv[2] = 1.0f / (q0.z + q1.z + q2.z + q3.z);
      cinv[3] = 1.0f / (q0.w + q1.w + q2.w + q3.w);
    }

    // ---- heatmap write + argmax (stores never waited on) ----
    float best = -1.0f; int bidx = 0;
    float* outh = out + (size_t)m * 4096;
#pragma unroll
    for (int i = 0; i < 4; ++i) {
      float ri = rinv[i];
      float4 h;
      h.x = acc[i][0] * acc[i][0] * ri * cinv[0];
      h.y = acc[i][1] * acc[i][1] * ri * cinv[1];
      h.z = acc[i][2] * acc[i][2] * ri * cinv[2];
      h.w = acc[i][3] * acc[i][3] * ri * cinv[3];
      int base = (l4 + i) * 64 + s4;
      *(float4*)(outh + base) = h;
      if (h.x > best) { best = h.x; bidx = base; }
      if (h.y > best) { best = h.y; bidx = base + 1; }
      if (h.z > best) { best = h.z; bidx = base + 2; }
      if (h.w > best) { best = h.w; bidx = base + 3; }
    }
#pragma unroll
    for (int off = 32; off; off >>= 1) {
      float ov = __shfl_xor(best, off);
      int   oi = __shfl_xor(bidx, off);
      if (ov > best || (ov == best && oi < bidx)) { best = ov; bidx = oi; }
    }
    if (lane == 0) { redv[wave] = best; redi[wave] = bidx; }
    asm volatile("s_waitcnt lgkmcnt(0)" ::: "memory");   // B6
    __builtin_amdgcn_s_barrier();
    asm volatile("" ::: "memory");

    // all threads reduce redundantly (broadcast LDS reads); defer the writes
    float fbv = redv[0]; int fbi = redi[0];
#pragma unroll
    for (int w = 1; w < 4; ++w) {
      float ov = redv[w]; int oi = redi[w];
      if (ov > fbv || (ov == fbv && oi < fbi)) { fbv = ov; fbi = oi; }
    }
    const unsigned long long v =
        (unsigned long long)((unsigned)(fbi >> 6) | ((unsigned)(fbi & 63) << 6));
    if (it < 4) pk0 |= v << (12 * it);
    else        pk1 |= v << (12 * (it - 4));
  }

  // ---- epilogue: scalar outputs, one m per lane (wave 0, lanes 0..ITERS-1) ----
  if (t < ITERS) {
    const int mi = m0 + t;
    const unsigned vv =
        (unsigned)(((t < 4) ? (pk0 >> (12 * t)) : (pk1 >> (12 * (t - 4)))) & 0xFFFull);
    const int i0 = vv & 63, i1 = (vv >> 6) & 63;
    float* oS = out + (size_t)M * 4096;
    oS[mi]         = (float)i0;                        // idxes0
    oS[M + mi]     = (float)i1;                        // idxes1
    oS[2 * M + 2 * mi + 0] = (float)(i0 & 7) - 3.5f;   // biases0.x
    oS[2 * M + 2 * mi + 1] = (float)(i0 >> 3) - 3.5f;  // biases0.y
    oS[4 * M + 2 * mi + 0] = (float)(i1 & 7) - 3.5f;   // biases1.x
    oS[4 * M + 2 * mi + 1] = (float)(i1 >> 3) - 3.5f;  // biases1.y
  }
}

// ---------------- K2: reg refinement (reads idx K1 wrote) ----------------
// One wave per m; lane = reg channel. Latency-bound gather.
__global__ __launch_bounds__(256, 8) void fm_reg_kernel(
    const float* __restrict__ feat0, const float* __restrict__ feat1,
    float* __restrict__ out, int M)
{
  const int lane = threadIdx.x & 63;
  const int mw   = blockIdx.x * 4 + (threadIdx.x >> 6);
  if (mw >= M) return;

  float* const oS = out + (size_t)M * 4096;
  const int i0 = (int)oS[mw];
  const int i1 = (int)oS[M + mw];

  const float* f0p = feat0 + (size_t)mw * 8192;
  const float* f1p = feat1 + (size_t)mw * 12800;

  const float rf0 = f0p[i0 * 128 + 64 + lane];
  const int r0 = i1 >> 3, c0 = i1 & 7;

  float p[9];
#pragma unroll
  for (int a = 0; a < 3; ++a)
#pragma unroll
    for (int b = 0; b < 3; ++b)
      p[a * 3 + b] = f1p[((r0 + a) * 10 + (c0 + b)) * 128 + 64 + lane] * rf0;

#pragma unroll
  for (int r = 0; r < 9; ++r)
#pragma unroll
    for (int off = 32; off; off >>= 1) p[r] += __shfl_xor(p[r], off);

  if (lane == 0) {
    float mx = p[0];
#pragma unroll
    for (int r = 1; r < 9; ++r) mx = fmaxf(mx, p[r]);
    float e[9], ssum = 0.0f;
#pragma unroll
    for (int r = 0; r < 9; ++r) { e[r] = __expf((p[r] - mx) * 0.125f); ssum += e[r]; }
    float inv = 1.0f / ssum, bx = 0.0f, by = 0.0f;
#pragma unroll
    for (int r = 0; r < 9; ++r) {
      float w = e[r] * inv;
      bx += w * (float)((r % 3) - 1);
      by += w * (float)((r / 3) - 1);
    }
    oS[6 * M + 2 * mw + 0] = bx;
    oS[6 * M + 2 * mw + 1] = by;
  }
}

extern "C" void kernel_launch(void* const* d_in, const int* in_sizes, int n_in,
                              void* d_out, int out_size, void* d_ws, size_t ws_size,
                              hipStream_t stream) {
  const float* f0 = (const float*)d_in[0];
  const float* f1 = (const float*)d_in[1];
  float* out = (float*)d_out;
  int M = in_sizes[0] / 8192;  // 64*128 per row
  fm_main_kernel<<<dim3(M / ITERS), dim3(256), 0, stream>>>(f0, f1, out, M);
  fm_reg_kernel<<<dim3((M + 3) / 4), dim3(256), 0, stream>>>(f0, f1, out, M);
}

// Round 12
// 237.102 us; speedup vs baseline: 17.6902x; 17.6902x over previous
//
#include <hip/hip_runtime.h>

// Async global->LDS, 16B per lane. Dest = wave-uniform base + lane*16.
__device__ __forceinline__ void gload_lds16(const float* g, float* l) {
  __builtin_amdgcn_global_load_lds(
      (const __attribute__((address_space(1))) unsigned int*)g,
      (__attribute__((address_space(3))) unsigned int*)l, 16, 0, 0);
}

// ---------------- K1: sim + dual softmax + heatmap + argmax ----------------
// One m per block (16384 independent blocks). LDS [half][row][32] layout,
// source-side XOR swizzle e(p) = (p>>2)&7 applied to quad index within half.
// Validated optimum (238 us): counted-vmcnt h0/h1 split, in-register softmax,
// lgkm-only barriers after staging, K2 split out.
__global__ __launch_bounds__(256, 4) void fm_main_kernel(
    const float* __restrict__ feat0, const float* __restrict__ feat1,
    float* __restrict__ out, int M)
{
  const int t    = threadIdx.x;
  const int lane = t & 63;
  const int wave = t >> 6;

  __shared__ __align__(16) float sA[4096];      // [2][64][32] halves of cls_f0
  __shared__ __align__(16) float sB[4096];      // [2][64][32] halves of cls_f1 inner
  __shared__ __align__(16) float colps[4][64];  // per-wave col-sum partials
  __shared__ float redv[4];
  __shared__ int   redi[4];

  const int m = blockIdx.x;
  const float* f0m = feat0 + (size_t)m * 8192;   // 64*128
  const float* f1m = feat1 + (size_t)m * 12800;  // 100*128

  // ---- stage: 8 gload_lds per wave, h0 (c<32) first, then h1 ----
  const int pr = lane >> 3;   // row within 8-row chunk
  const int q  = lane & 7;    // slot quad within half
#pragma unroll
  for (int h = 0; h < 2; ++h) {
#pragma unroll
    for (int k = 0; k < 2; ++k) {
      const int p0 = wave * 16 + k * 8;
      const int p  = p0 + pr;
      const int gq = q ^ ((p >> 2) & 7);          // source-side swizzle
      gload_lds16(f0m + p * 128 + h * 32 + gq * 4, &sA[h * 2048 + p0 * 32]);
      const int r = ((p >> 3) + 1) * 10 + (p & 7) + 1;  // inner 8x8 of 10x10
      gload_lds16(f1m + r * 128 + h * 32 + gq * 4, &sB[h * 2048 + p0 * 32]);
    }
  }

  // address setup under the load shadow
  const int st = t & 15, lt = t >> 4;
  const int s4 = st << 2, l4 = lt << 2;
  const int ea = lt & 7, eb = st & 7;   // read-side XOR (= e(p) of owned rows)

  float acc[4][4] = {};

  // ---- h0 ready (oldest 4 loads), all waves -> compute c<32 while h1 drains ----
  asm volatile("s_waitcnt vmcnt(4)" ::: "memory");
  __builtin_amdgcn_s_barrier();
  asm volatile("" ::: "memory");

#pragma unroll
  for (int c8 = 0; c8 < 8; ++c8) {
    const int qa = (c8 ^ ea) << 2, qb = (c8 ^ eb) << 2;
    float4 a[4], b[4];
#pragma unroll
    for (int i = 0; i < 4; ++i) a[i] = *(const float4*)(&sA[(l4 + i) * 32 + qa]);
#pragma unroll
    for (int j = 0; j < 4; ++j) b[j] = *(const float4*)(&sB[(s4 + j) * 32 + qb]);
#pragma unroll
    for (int i = 0; i < 4; ++i)
#pragma unroll
      for (int j = 0; j < 4; ++j)
        acc[i][j] += a[i].x * b[j].x + a[i].y * b[j].y + a[i].z * b[j].z + a[i].w * b[j].w;
  }

  // ---- h1 ready ----
  asm volatile("s_waitcnt vmcnt(0)" ::: "memory");
  __builtin_amdgcn_s_barrier();
  asm volatile("" ::: "memory");

#pragma unroll
  for (int c8 = 0; c8 < 8; ++c8) {
    const int qa = (c8 ^ ea) << 2, qb = (c8 ^ eb) << 2;
    float4 a[4], b[4];
#pragma unroll
    for (int i = 0; i < 4; ++i) a[i] = *(const float4*)(&sA[2048 + (l4 + i) * 32 + qa]);
#pragma unroll
    for (int j = 0; j < 4; ++j) b[j] = *(const float4*)(&sB[2048 + (s4 + j) * 32 + qb]);
#pragma unroll
    for (int i = 0; i < 4; ++i)
#pragma unroll
      for (int j = 0; j < 4; ++j)
        acc[i][j] += a[i].x * b[j].x + a[i].y * b[j].y + a[i].z * b[j].z + a[i].w * b[j].w;
  }

  // ---- softmax stats, unshifted: e = exp(sim/64); heat = e^2 * rinv * cinv ----
  float rinv[4];
#pragma unroll
  for (int i = 0; i < 4; ++i) {
    float rs = 0.0f;
#pragma unroll
    for (int j = 0; j < 4; ++j) { acc[i][j] = __expf(acc[i][j] * 0.015625f); rs += acc[i][j]; }
#pragma unroll
    for (int off = 1; off <= 8; off <<= 1) rs += __shfl_xor(rs, off);
    rinv[i] = 1.0f / rs;
  }
  {
    float cps[4];
#pragma unroll
    for (int j = 0; j < 4; ++j) {
      float cs = acc[0][j] + acc[1][j] + acc[2][j] + acc[3][j];
      cs += __shfl_xor(cs, 16);
      cs += __shfl_xor(cs, 32);
      cps[j] = cs;
    }
    if (lane < 16) *(float4*)(&colps[wave][s4]) = make_float4(cps[0], cps[1], cps[2], cps[3]);
  }
  asm volatile("s_waitcnt lgkmcnt(0)" ::: "memory");
  __builtin_amdgcn_s_barrier();
  asm volatile("" ::: "memory");

  float cinv[4];
  {
    float4 q0 = *(const float4*)(&colps[0][s4]);
    float4 q1 = *(const float4*)(&colps[1][s4]);
    float4 q2 = *(const float4*)(&colps[2][s4]);
    float4 q3 = *(const float4*)(&colps[3][s4]);
    cinv[0] = 1.0f / (q0.x + q1.x + q2.x + q3.x);
    cinv[1] = 1.0f / (q0.y + q1.y + q2.y + q3.y);
    cinv[2] = 1.0f / (q0.z + q1.z + q2.z + q3.z);
    cinv[3] = 1.0f / (q0.w + q1.w + q2.w + q3.w);
  }

  // ---- heatmap write + argmax (stores stay in flight across lgkm barriers) ----
  float best = -1.0f; int bidx = 0;
  float* outh = out + (size_t)m * 4096;
#pragma unroll
  for (int i = 0; i < 4; ++i) {
    float ri = rinv[i];
    float4 h;
    h.x = acc[i][0] * acc[i][0] * ri * cinv[0];
    h.y = acc[i][1] * acc[i][1] * ri * cinv[1];
    h.z = acc[i][2] * acc[i][2] * ri * cinv[2];
    h.w = acc[i][3] * acc[i][3] * ri * cinv[3];
    int base = (l4 + i) * 64 + s4;
    *(float4*)(outh + base) = h;
    if (h.x > best) { best = h.x; bidx = base; }
    if (h.y > best) { best = h.y; bidx = base + 1; }
    if (h.z > best) { best = h.z; bidx = base + 2; }
    if (h.w > best) { best = h.w; bidx = base + 3; }
  }
#pragma unroll
  for (int off = 32; off; off >>= 1) {
    float ov = __shfl_xor(best, off);
    int   oi = __shfl_xor(bidx, off);
    if (ov > best || (ov == best && oi < bidx)) { best = ov; bidx = oi; }
  }
  if (lane == 0) { redv[wave] = best; redi[wave] = bidx; }
  asm volatile("s_waitcnt lgkmcnt(0)" ::: "memory");
  __builtin_amdgcn_s_barrier();
  asm volatile("" ::: "memory");

  if (t == 0) {
    float fbv = redv[0]; int fbi = redi[0];
#pragma unroll
    for (int w = 1; w < 4; ++w) {
      float ov = redv[w]; int oi = redi[w];
      if (ov > fbv || (ov == fbv && oi < fbi)) { fbv = ov; fbi = oi; }
    }
    const int i0 = fbi >> 6, i1 = fbi & 63;
    float* oS = out + (size_t)M * 4096;
    oS[m]         = (float)i0;                       // idxes0
    oS[M + m]     = (float)i1;                       // idxes1
    oS[2 * M + 2 * m + 0] = (float)(i0 & 7) - 3.5f;  // biases0.x
    oS[2 * M + 2 * m + 1] = (float)(i0 >> 3) - 3.5f; // biases0.y
    oS[4 * M + 2 * m + 0] = (float)(i1 & 7) - 3.5f;  // biases1.x
    oS[4 * M + 2 * m + 1] = (float)(i1 >> 3) - 3.5f; // biases1.y
  }
}

// ---------------- K2: reg refinement (reads idx K1 wrote) ----------------
// One wave per m; lane = reg channel. Latency-bound gather.
__global__ __launch_bounds__(256, 8) void fm_reg_kernel(
    const float* __restrict__ feat0, const float* __restrict__ feat1,
    float* __restrict__ out, int M)
{
  const int lane = threadIdx.x & 63;
  const int mw   = blockIdx.x * 4 + (threadIdx.x >> 6);
  if (mw >= M) return;

  float* const oS = out + (size_t)M * 4096;
  const int i0 = (int)oS[mw];
  const int i1 = (int)oS[M + mw];

  const float* f0p = feat0 + (size_t)mw * 8192;
  const float* f1p = feat1 + (size_t)mw * 12800;

  const float rf0 = f0p[i0 * 128 + 64 + lane];
  const int r0 = i1 >> 3, c0 = i1 & 7;

  float p[9];
#pragma unroll
  for (int a = 0; a < 3; ++a)
#pragma unroll
    for (int b = 0; b < 3; ++b)
      p[a * 3 + b] = f1p[((r0 + a) * 10 + (c0 + b)) * 128 + 64 + lane] * rf0;

#pragma unroll
  for (int r = 0; r < 9; ++r)
#pragma unroll
    for (int off = 32; off; off >>= 1) p[r] += __shfl_xor(p[r], off);

  if (lane == 0) {
    float mx = p[0];
#pragma unroll
    for (int r = 1; r < 9; ++r) mx = fmaxf(mx, p[r]);
    float e[9], ssum = 0.0f;
#pragma unroll
    for (int r = 0; r < 9; ++r) { e[r] = __expf((p[r] - mx) * 0.125f); ssum += e[r]; }
    float inv = 1.0f / ssum, bx = 0.0f, by = 0.0f;
#pragma unroll
    for (int r = 0; r < 9; ++r) {
      float w = e[r] * inv;
      bx += w * (float)((r % 3) - 1);
      by += w * (float)((r / 3) - 1);
    }
    oS[6 * M + 2 * mw + 0] = bx;
    oS[6 * M + 2 * mw + 1] = by;
  }
}

extern "C" void kernel_launch(void* const* d_in, const int* in_sizes, int n_in,
                              void* d_out, int out_size, void* d_ws, size_t ws_size,
                              hipStream_t stream) {
  const float* f0 = (const float*)d_in[0];
  const float* f1 = (const float*)d_in[1];
  float* out = (float*)d_out;
  int M = in_sizes[0] / 8192;  // 64*128 per row
  fm_main_kernel<<<dim3(M), dim3(256), 0, stream>>>(f0, f1, out, M);
  fm_reg_kernel<<<dim3((M + 3) / 4), dim3(256), 0, stream>>>(f0, f1, out, M);
}